// Round 18
// baseline (157.221 us; speedup 1.0000x reference)
//
#include <hip/hip_runtime.h>
#include <hip/hip_bf16.h>
#include <hip/hip_fp8.h>

#define N_NODES 50000
#define N_EDGES 800000
#define HB 3125   // hist/scatter blocks: 800000/256
#define GA 1562   // gemm1 blocks in D2 (16 rows each)
#define GB2 1563  // gemm1 blocks in D4 ; GA+GB2 = 3125 = 50000/16
#define NBS 49    // scan blocks: ceil(50000/1024)

static constexpr float SCALE = 0.17677669529663687f; // 1/sqrt(32)

typedef __attribute__((ext_vector_type(8))) short bf16x8;
typedef __attribute__((ext_vector_type(4))) float f32x4;
typedef __attribute__((ext_vector_type(2))) float f32x2;
#define MFMA16 __builtin_amdgcn_mfma_f32_16x16x32_bf16
#define CVT8 __builtin_amdgcn_cvt_pk_f32_fp8

static __device__ inline unsigned short f2bf(float f) {
    __hip_bfloat16 h = __float2bfloat16(f);
    return __builtin_bit_cast(unsigned short, h);
}
static __device__ inline unsigned char f2fp8(float f) {
    __hip_fp8_e4m3 h(f); // OCP e4m3fn, RNE
    return __builtin_bit_cast(unsigned char, h);
}
// packed pair of bf16 (one u32) -> f32x2
static __device__ inline f32x2 bfp2(unsigned u) {
    f32x2 r;
    r[0] = __uint_as_float(u << 16);
    r[1] = __uint_as_float(u & 0xffff0000u);
    return r;
}

// ---------------- 16-row GEMM1 block (low-VGPR: acc[4] per column-half) ----------------

static __device__ __forceinline__ void gemm16(
    int rb, unsigned char* smem,
    const float* __restrict__ x, const unsigned short* __restrict__ Wf1,
    const float* __restrict__ bq, const float* __restrict__ bk,
    const float* __restrict__ bv, const float* __restrict__ bs,
    unsigned short* __restrict__ qs1, unsigned char* __restrict__ kv8)
{
    int w = threadIdx.x >> 6;
    int l = threadIdx.x & 63;
    int lr = l & 15, lk = l >> 4;
    unsigned short* xs = (unsigned short*)smem;      // [16][72]
    unsigned char* ep = smem + 2560;                 // wave w: ep + w*2304
    {
        int row = threadIdx.x >> 4, c = (threadIdx.x & 15) * 4;
        float4 f = *(const float4*)(x + (size_t)(rb + row) * 64 + c);
        unsigned short* dp = xs + row * 72 + c;
        dp[0] = f2bf(f.x); dp[1] = f2bf(f.y); dp[2] = f2bf(f.z); dp[3] = f2bf(f.w);
    }
    __syncthreads();
    bf16x8 a0 = *(const bf16x8*)(xs + lr * 72 + lk * 8);
    bf16x8 a1 = *(const bf16x8*)(xs + lr * 72 + 32 + lk * 8);
    const float* bptr = (w == 0) ? bq : (w == 1) ? bk : (w == 2) ? bv : bs;
#pragma unroll
    for (int hf = 0; hf < 2; ++hf) {
        f32x4 acc[4];
#pragma unroll
        for (int nt4 = 0; nt4 < 4; ++nt4) acc[nt4] = (f32x4){0.f, 0.f, 0.f, 0.f};
#pragma unroll
        for (int nt4 = 0; nt4 < 4; ++nt4) {
            int nt = hf * 4 + nt4;
            bf16x8 b0 = *(const bf16x8*)(Wf1 + (size_t)((w * 8 + nt) * 1024) + l * 8);
            bf16x8 b1 = *(const bf16x8*)(Wf1 + (size_t)((w * 8 + nt) * 1024 + 512) + l * 8);
            acc[nt4] = MFMA16(a0, b0, acc[nt4], 0, 0, 0);
            acc[nt4] = MFMA16(a1, b1, acc[nt4], 0, 0, 0);
        }
        if (w == 1 || w == 2) { // k,v -> fp8 into interleaved kv8 (groups 8hf..8hf+8)
            unsigned char* lb = ep + w * 2304;   // [16][72] bytes
#pragma unroll
            for (int nt4 = 0; nt4 < 4; ++nt4) {
                float bias = bptr[hf * 64 + nt4 * 16 + lr];
#pragma unroll
                for (int i = 0; i < 4; ++i)
                    lb[(lk * 4 + i) * 72 + nt4 * 16 + lr] = f2fp8(acc[nt4][i] + bias);
            }
            int voff = (w == 2) ? 8 : 0;
            int g = lr & 7, b = lr >> 3;
#pragma unroll
            for (int p = 0; p < 2; ++p) {
                int rl = p * 8 + lk * 2 + b;
                uint2 val = *(const uint2*)(lb + rl * 72 + g * 8);
                *(uint2*)(kv8 + (size_t)(rb + rl) * 256 + (hf * 8 + g) * 16 + voff) = val;
            }
        } else {                // q,s -> bf16 qs1 (cols hf*64..hf*64+64)
            unsigned short* ls = (unsigned short*)(ep + w * 2304); // [16][72] shorts -> 2304B ✓
#pragma unroll
            for (int nt4 = 0; nt4 < 4; ++nt4) {
                float bias = bptr[hf * 64 + nt4 * 16 + lr];
#pragma unroll
                for (int i = 0; i < 4; ++i)
                    ls[(lk * 4 + i) * 72 + nt4 * 16 + lr] = f2bf(acc[nt4][i] + bias);
            }
            int base = (w == 0) ? 0 : 128;
#pragma unroll
            for (int p = 0; p < 4; ++p) {
                int rl = p * 4 + lk;
                uint2 val = *(const uint2*)(ls + rl * 72 + lr * 4);
                *(uint2*)(qs1 + (size_t)(rb + rl) * 256 + base + hf * 64 + lr * 4) = val;
            }
        }
    }
}

// ---------------- D1: weight fragments + cnt8/ctr zero ----------------

__global__ __launch_bounds__(256) void k_wf(
    const float* __restrict__ Wq1, const float* __restrict__ Wk1,
    const float* __restrict__ Wv1, const float* __restrict__ Ws1,
    const float* __restrict__ Wq2, const float* __restrict__ Wk2,
    const float* __restrict__ Wv2, const float* __restrict__ Ws2,
    unsigned short* __restrict__ Wf1, unsigned short* __restrict__ Wf2,
    int* __restrict__ cnt8)
{
    int id = blockIdx.x * 256 + threadIdx.x;
    if (id < N_NODES * 8 + 64) cnt8[id] = 0;  // 8 planes + ctr tail
    if (id < 32768) {
        int j = id & 7, l = (id >> 3) & 63, ks = (id >> 9) & 1, nt = (id >> 10) & 7, m = (id >> 13) & 3;
        const float* W = (m == 0) ? Wq1 : (m == 1) ? Wk1 : (m == 2) ? Wv1 : Ws1;
        int k = ks * 32 + ((l >> 4) << 3) + j;
        int c = nt * 16 + (l & 15);
        Wf1[id] = f2bf(W[k * 128 + c]);
    } else if (id < 49152) {
        int id2 = id - 32768;
        int j = id2 & 7, l = (id2 >> 3) & 63, ks = (id2 >> 9) & 3, g = (id2 >> 11) & 7;
        int m = g >> 1, t = g & 1;
        const float* W = (m == 0) ? Wq2 : (m == 1) ? Wk2 : (m == 2) ? Wv2 : Ws2;
        int k = ks * 32 + ((l >> 4) << 3) + j;
        int c = t * 16 + (l & 15);
        Wf2[id2] = f2bf(W[k * 32 + c]);
    }
}

// ---------------- D2: plane-replica hist (blocks 0..HB) || GEMM1 rows [0, GA*16) ----------------
// 8 replica PLANES (different cache lines, unlike R17's same-line int4 replicas):
// per-line atomic ops drop 256 -> 32. Discriminating test of LINE-level serialization.

__global__ __launch_bounds__(256) void k_hg2(
    const int* __restrict__ dst, int* __restrict__ cnt8, int* __restrict__ rank,
    const float* __restrict__ x, const unsigned short* __restrict__ Wf1,
    const float* __restrict__ bq, const float* __restrict__ bk,
    const float* __restrict__ bv, const float* __restrict__ bs,
    unsigned short* __restrict__ qs1, unsigned char* __restrict__ kv8)
{
    __shared__ unsigned char smem[2560 + 4 * 2304];
    if (blockIdx.x < HB) {
        int e = blockIdx.x * 256 + threadIdx.x; // E exact multiple of 256
        rank[e] = atomicAdd(&cnt8[(e & 7) * N_NODES + dst[e]], 1);
        return;
    }
    gemm16((blockIdx.x - HB) * 16, smem, x, Wf1, bq, bk, bv, bs, qs1, kv8);
}

// ---------------- D3: scan over plane counts ----------------
// row[v] = block-local exclusive prefix of node totals (as before).
// cnt8[r][v] is overwritten with (row_local + plane prefix) so scatter needs ONE gather.

__global__ __launch_bounds__(256) void k_scan(int* __restrict__ cnt8,
                                              int* __restrict__ row,
                                              int* __restrict__ bsum,
                                              int* __restrict__ boff,
                                              int* __restrict__ ctr, int n) {
    __shared__ int wsum[4];
    __shared__ int lastBlk;
    int t = threadIdx.x;
    int base = blockIdx.x * 1024 + t * 4;
    int c[4][8];
    int tot[4];
#pragma unroll
    for (int i = 0; i < 4; ++i) {
        int v = base + i;
        tot[i] = 0;
        if (v < n) {
#pragma unroll
            for (int r = 0; r < 8; ++r) {
                c[i][r] = cnt8[r * N_NODES + v];
                tot[i] += c[i][r];
            }
        }
    }
    int s = tot[0] + tot[1] + tot[2] + tot[3];
    int lane = t & 63, wid = t >> 6;
    int sc = s;
#pragma unroll
    for (int d = 1; d < 64; d <<= 1) {
        int o = __shfl_up(sc, d);
        if (lane >= d) sc += o;
    }
    if (lane == 63) wsum[wid] = sc;
    __syncthreads();
    int woff = 0;
    for (int w = 0; w < wid; ++w) woff += wsum[w];
    int run = woff + sc - s; // exclusive prefix for this thread's first node
#pragma unroll
    for (int i = 0; i < 4; ++i) {
        int v = base + i;
        if (v < n) {
            row[v] = run;
#pragma unroll
            for (int r = 0; r < 8; ++r) {
                cnt8[r * N_NODES + v] = run;
                run += c[i][r];
            }
        }
    }
    if (t == 255) {
        bsum[blockIdx.x] = woff + sc;
        __threadfence();
        lastBlk = (atomicAdd(ctr, 1) == NBS - 1);
    }
    __syncthreads();
    if (lastBlk && t < 64) {
        __threadfence();
        int v = (t < NBS) ? ((volatile int*)bsum)[t] : 0;
        int sc2 = v;
#pragma unroll
        for (int d = 1; d < 64; d <<= 1) {
            int o = __shfl_up(sc2, d);
            if (t >= d) sc2 += o;
        }
        boff[t] = sc2 - v; // exclusive block offset
        if (t == (N_NODES >> 10)) row[N_NODES] = N_EDGES - (sc2 - v);
    }
}

// ---------------- D4: GEMM1 rows [GA*16, 50000) (blocks 0..GB2) || scatter ----------------
// scatter: position = cnt8[r][de] (= row_local + plane prefix) + boff + rank.

__global__ __launch_bounds__(256) void k_sg2(
    const int* __restrict__ src, const int* __restrict__ dst,
    const int* __restrict__ cnt8, const int* __restrict__ boff,
    const int* __restrict__ rank, int* __restrict__ col,
    const float* __restrict__ x, const unsigned short* __restrict__ Wf1,
    const float* __restrict__ bq, const float* __restrict__ bk,
    const float* __restrict__ bv, const float* __restrict__ bs,
    unsigned short* __restrict__ qs1, unsigned char* __restrict__ kv8)
{
    __shared__ unsigned char smem[2560 + 4 * 2304];
    if (blockIdx.x >= GB2) {
        int e = (blockIdx.x - GB2) * 256 + threadIdx.x;
        int de = dst[e];
        col[cnt8[(e & 7) * N_NODES + de] + boff[de >> 10] + rank[e]] = src[e];
        return;
    }
    gemm16((GA + blockIdx.x) * 16, smem, x, Wf1, bq, bk, bv, bs, qs1, kv8);
}

// ---------------- GEMM 2 (MFMA): h1b[N,128]bf16 @ {Wq,Wk,Wv,Ws}[128,32] + b ----------------

__global__ __launch_bounds__(256) void k_gemm2m(
    const unsigned short* __restrict__ h1b, const unsigned short* __restrict__ Wf2,
    const float* __restrict__ bq, const float* __restrict__ bk,
    const float* __restrict__ bv, const float* __restrict__ bs,
    unsigned short* __restrict__ qs2, unsigned char* __restrict__ k82,
    unsigned short* __restrict__ v2, int n)
{
    __shared__ unsigned short lds[4][32][72]; // 18.4 KB
    int w = threadIdx.x >> 6;
    int l = threadIdx.x & 63;
    int half = w & 1;
    int rb = blockIdx.x * 64 + (w >> 1) * 32;
    int lr = l & 15, lk = l >> 4;
    f32x4 acc[2][4];
#pragma unroll
    for (int mt = 0; mt < 2; ++mt)
#pragma unroll
        for (int nt = 0; nt < 4; ++nt) acc[mt][nt] = (f32x4){0.f, 0.f, 0.f, 0.f};
#pragma unroll
    for (int ks = 0; ks < 4; ++ks) {
        bf16x8 a[2];
#pragma unroll
        for (int mt = 0; mt < 2; ++mt) {
            int r = rb + mt * 16 + lr;
            if (r >= n) r = n - 1;
            a[mt] = *(const bf16x8*)(h1b + (size_t)r * 128 + ks * 32 + lk * 8);
        }
#pragma unroll
        for (int nt = 0; nt < 4; ++nt) {
            int g = half * 4 + nt;
            bf16x8 b = *(const bf16x8*)(Wf2 + (size_t)((g * 4 + ks) * 512 + l * 8));
            acc[0][nt] = MFMA16(a[0], b, acc[0][nt], 0, 0, 0);
            acc[1][nt] = MFMA16(a[1], b, acc[1][nt], 0, 0, 0);
        }
    }
#pragma unroll
    for (int nt = 0; nt < 4; ++nt) {
        int g = half * 4 + nt;
        int mat = g >> 1;
        int c = (g * 16 + lr) & 31;
        const float* bp = (mat == 0) ? bq : (mat == 1) ? bk : (mat == 2) ? bv : bs;
        float bias = bp[c];
#pragma unroll
        for (int mt = 0; mt < 2; ++mt)
#pragma unroll
            for (int i = 0; i < 4; ++i)
                lds[w][mt * 16 + lk * 4 + i][nt * 16 + lr] = f2bf(acc[mt][nt][i] + bias);
    }
    int rl8 = l >> 3, ci = (l & 7) * 4;
#pragma unroll
    for (int p = 0; p < 4; ++p) {
        int rl = p * 8 + rl8;
        int r = rb + rl;
        if (r < n) {
            uint2 va = *(const uint2*)&lds[w][rl][ci];
            uint2 vb = *(const uint2*)&lds[w][rl][32 + ci];
            if (half == 0) {
                *(uint2*)(qs2 + (size_t)r * 64 + ci) = va;              // q bf16
                unsigned pk =                                            // k -> fp8
                      (unsigned)f2fp8(__uint_as_float(vb.x << 16))
                    | ((unsigned)f2fp8(__uint_as_float(vb.x & 0xffff0000u)) << 8)
                    | ((unsigned)f2fp8(__uint_as_float(vb.y << 16)) << 16)
                    | ((unsigned)f2fp8(__uint_as_float(vb.y & 0xffff0000u)) << 24);
                *(unsigned*)(k82 + (size_t)r * 32 + ci) = pk;
            } else {
                *(uint2*)(v2 + (size_t)r * 32 + ci) = va;               // v bf16
                *(uint2*)(qs2 + (size_t)r * 64 + 32 + ci) = vb;         // s bf16
            }
        }
    }
}

// ---------------- Layer-1 attention aggregate (measured floor: do not touch) ----------------

__global__ __launch_bounds__(256) void k_agg1(
    const unsigned short* __restrict__ qs1, const unsigned char* __restrict__ kv8,
    const int* __restrict__ row, const int* __restrict__ boff,
    const int* __restrict__ col, uint4* __restrict__ h1b, int n)
{
    int i = blockIdx.x * 4 + (threadIdx.x >> 6);
    if (i >= n) return;
    int lane = threadIdx.x & 63;
    int slot = lane >> 4, w = lane & 15;
    f32x2 q2[4];
    {
        uint4 qu = *(const uint4*)(qs1 + (size_t)i * 256 + w * 8);
        q2[0] = bfp2(qu.x); q2[1] = bfp2(qu.y); q2[2] = bfp2(qu.z); q2[3] = bfp2(qu.w);
    }
    f32x2 acc2[4] = {};
    float d = 0.f;
    int s = row[i] + boff[i >> 10];
    int e = row[i + 1] + boff[(i + 1) >> 10];
    for (int t = s; t < e; t += 8) {
        int ta = t + slot, tb = t + 4 + slot;
        bool va = ta < e, vb = tb < e;
        int ja = col[va ? ta : s];
        int jb = col[vb ? tb : s];
        uint4 A = *(const uint4*)(kv8 + (size_t)ja * 256 + w * 16);
        uint4 B = *(const uint4*)(kv8 + (size_t)jb * 256 + w * 16);
        f32x2 pa = CVT8(A.x, false) * q2[0];
        pa += CVT8(A.x, true)  * q2[1];
        pa += CVT8(A.y, false) * q2[2];
        pa += CVT8(A.y, true)  * q2[3];
        f32x2 pb = CVT8(B.x, false) * q2[0];
        pb += CVT8(B.x, true)  * q2[1];
        pb += CVT8(B.y, false) * q2[2];
        pb += CVT8(B.y, true)  * q2[3];
        float la = pa[0] + pa[1];
        float lb = pb[0] + pb[1];
        la += __shfl_xor(la, 1);  lb += __shfl_xor(lb, 1);
        la += __shfl_xor(la, 2);  lb += __shfl_xor(lb, 2);
        float wa = va ? __expf(la * SCALE) : 0.f;
        float wb = vb ? __expf(lb * SCALE) : 0.f;
        d += wa + wb;
        f32x2 wa2 = (f32x2){wa, wa};
        f32x2 wb2 = (f32x2){wb, wb};
        acc2[0] += wa2 * CVT8(A.z, false);
        acc2[1] += wa2 * CVT8(A.z, true);
        acc2[2] += wa2 * CVT8(A.w, false);
        acc2[3] += wa2 * CVT8(A.w, true);
        acc2[0] += wb2 * CVT8(B.z, false);
        acc2[1] += wb2 * CVT8(B.z, true);
        acc2[2] += wb2 * CVT8(B.w, false);
        acc2[3] += wb2 * CVT8(B.w, true);
    }
    float acc[8] = {acc2[0][0], acc2[0][1], acc2[1][0], acc2[1][1],
                    acc2[2][0], acc2[2][1], acc2[3][0], acc2[3][1]};
#pragma unroll
    for (int m = 16; m <= 32; m <<= 1) {
        d += __shfl_xor(d, m);
#pragma unroll
        for (int c = 0; c < 8; ++c) acc[c] += __shfl_xor(acc[c], m);
    }
    if (slot == 0) {
        float inv = (d > 0.f) ? 1.f / d : 0.f;
        uint4 su = *(const uint4*)(qs1 + (size_t)i * 256 + 128 + w * 8);
        f32x2 sv[4] = {bfp2(su.x), bfp2(su.y), bfp2(su.z), bfp2(su.w)};
        unsigned o[4];
#pragma unroll
        for (int p = 0; p < 4; ++p) {
            float rx = acc[2 * p] * inv + sv[p][0];
            float ry = acc[2 * p + 1] * inv + sv[p][1];
            rx = (rx > 0.f) ? rx : expm1f(rx); // ELU
            ry = (ry > 0.f) ? ry : expm1f(ry);
            o[p] = ((unsigned)f2bf(ry) << 16) | (unsigned)f2bf(rx);
        }
        h1b[(size_t)i * 16 + w] = make_uint4(o[0], o[1], o[2], o[3]);
    }
}

// ---------------- Layer-2 attention aggregate ----------------

__global__ __launch_bounds__(256) void k_agg2(
    const unsigned short* __restrict__ qs2, const unsigned char* __restrict__ k82,
    const unsigned short* __restrict__ v2,
    const int* __restrict__ row, const int* __restrict__ boff,
    const int* __restrict__ col, float* __restrict__ out, int n)
{
    int i = blockIdx.x * 4 + (threadIdx.x >> 6);
    if (i >= n) return;
    int lane = threadIdx.x & 63;
    int slot = lane >> 2, qr = lane & 3;
    f32x2 q2[4];
    {
        uint4 qu = *(const uint4*)(qs2 + (size_t)i * 64 + qr * 8);
        q2[0] = bfp2(qu.x); q2[1] = bfp2(qu.y); q2[2] = bfp2(qu.z); q2[3] = bfp2(qu.w);
    }
    f32x2 acc2[4] = {};
    float d = 0.f;
    int s = row[i] + boff[i >> 10];
    int e = row[i + 1] + boff[(i + 1) >> 10];
    for (int t = s; t < e; t += 16) {
        int te = t + slot;
        bool va = te < e;
        int j = col[va ? te : s];
        uint2 ku = *(const uint2*)(k82 + (size_t)j * 32 + qr * 8);
        uint4 vu = *(const uint4*)(v2 + (size_t)j * 32 + qr * 8);
        f32x2 pp = CVT8(ku.x, false) * q2[0];
        pp += CVT8(ku.x, true)  * q2[1];
        pp += CVT8(ku.y, false) * q2[2];
        pp += CVT8(ku.y, true)  * q2[3];
        float lg = pp[0] + pp[1];
        lg += __shfl_xor(lg, 1);
        lg += __shfl_xor(lg, 2);
        float wv = va ? __expf(lg * SCALE) : 0.f;
        d += wv;
        f32x2 w2 = (f32x2){wv, wv};
        acc2[0] += w2 * bfp2(vu.x);
        acc2[1] += w2 * bfp2(vu.y);
        acc2[2] += w2 * bfp2(vu.z);
        acc2[3] += w2 * bfp2(vu.w);
    }
    float acc[8] = {acc2[0][0], acc2[0][1], acc2[1][0], acc2[1][1],
                    acc2[2][0], acc2[2][1], acc2[3][0], acc2[3][1]};
#pragma unroll
    for (int m = 4; m <= 32; m <<= 1) {
        d += __shfl_xor(d, m);
#pragma unroll
        for (int c = 0; c < 8; ++c) acc[c] += __shfl_xor(acc[c], m);
    }
    if (slot == 0) {
        float inv = (d > 0.f) ? 1.f / d : 0.f;
        uint4 su = *(const uint4*)(qs2 + (size_t)i * 64 + 32 + qr * 8);
        f32x2 sv[4] = {bfp2(su.x), bfp2(su.y), bfp2(su.z), bfp2(su.w)};
        float4 o0, o1;
        o0.x = acc[0] * inv + sv[0][0];
        o0.y = acc[1] * inv + sv[0][1];
        o0.z = acc[2] * inv + sv[1][0];
        o0.w = acc[3] * inv + sv[1][1];
        o1.x = acc[4] * inv + sv[2][0];
        o1.y = acc[5] * inv + sv[2][1];
        o1.z = acc[6] * inv + sv[3][0];
        o1.w = acc[7] * inv + sv[3][1];
        *(float4*)&out[(size_t)i * 32 + qr * 8] = o0;
        *(float4*)&out[(size_t)i * 32 + qr * 8 + 4] = o1;
    }
}

// ---------------- launch ----------------

extern "C" void kernel_launch(void* const* d_in, const int* in_sizes, int n_in,
                              void* d_out, int out_size, void* d_ws, size_t ws_size,
                              hipStream_t stream)
{
    const int N = N_NODES, E = N_EDGES;
    const float* x   = (const float*)d_in[0];
    const int* edge  = (const int*)d_in[1];
    const int* src   = edge;       // edge_index[0]
    const int* dst   = edge + E;   // edge_index[1]
    const float* Wq1 = (const float*)d_in[2];  const float* bq1 = (const float*)d_in[3];
    const float* Wk1 = (const float*)d_in[4];  const float* bk1 = (const float*)d_in[5];
    const float* Wv1 = (const float*)d_in[6];  const float* bv1 = (const float*)d_in[7];
    const float* Ws1 = (const float*)d_in[8];  const float* bs1 = (const float*)d_in[9];
    const float* Wq2 = (const float*)d_in[10]; const float* bq2 = (const float*)d_in[11];
    const float* Wk2 = (const float*)d_in[12]; const float* bk2 = (const float*)d_in[13];
    const float* Wv2 = (const float*)d_in[14]; const float* bv2 = (const float*)d_in[15];
    const float* Ws2 = (const float*)d_in[16]; const float* bs2 = (const float*)d_in[17];

    char* ws = (char*)d_ws;
    size_t off = 0;
    auto alloc = [&](size_t bytes) -> void* {
        void* p = ws + off;
        off += (bytes + 255) & ~(size_t)255;
        return p;
    };
    unsigned short* qs1 = (unsigned short*)alloc((size_t)N * 256 * 2); // 25.6 MB
    unsigned char*  kv8 = (unsigned char*)alloc((size_t)N * 256);      // 12.8 MB (k,v interleaved fp8)
    unsigned short* h1b = (unsigned short*)alloc((size_t)N * 128 * 2); // 12.8 MB
    unsigned short* qs2 = (unsigned short*)alloc((size_t)N * 64 * 2);  //  6.4 MB
    unsigned char*  k82 = (unsigned char*)alloc((size_t)N * 32);       //  1.6 MB (fp8 k2)
    unsigned short* v2  = (unsigned short*)alloc((size_t)N * 32 * 2);  //  3.2 MB (bf16 v2)
    unsigned short* Wf1 = (unsigned short*)alloc(32768 * 2);
    unsigned short* Wf2 = (unsigned short*)alloc(16384 * 2);
    int* row_ptr  = (int*)alloc((size_t)(N + 1) * 4);
    int* cnt8     = (int*)alloc((size_t)(N * 8 + 64) * 4); // 8 planes + ctr
    int* ctr      = cnt8 + N * 8;
    int* rank     = (int*)alloc((size_t)E * 4);
    int* colb     = (int*)alloc((size_t)E * 4);
    int* bsum     = (int*)alloc(64 * 4);
    int* boff     = (int*)alloc(64 * 4);

    int WFB = (N * 8 + 64 + 255) / 256; // 1563 blocks: cnt8 zero + both wfrag ranges

    k_wf<<<WFB, 256, 0, stream>>>(Wq1, Wk1, Wv1, Ws1, Wq2, Wk2, Wv2, Ws2,
                                  Wf1, Wf2, cnt8);
    k_hg2<<<HB + GA, 256, 0, stream>>>(dst, cnt8, rank,
                                       x, Wf1, bq1, bk1, bv1, bs1, qs1, kv8);
    k_scan<<<NBS, 256, 0, stream>>>(cnt8, row_ptr, bsum, boff, ctr, N);
    k_sg2<<<GB2 + HB, 256, 0, stream>>>(src, dst, cnt8, boff, rank, colb,
                                        x, Wf1, bq1, bk1, bv1, bs1, qs1, kv8);
    k_agg1<<<(N + 3) / 4, 256, 0, stream>>>(qs1, kv8, row_ptr, boff, colb, (uint4*)h1b, N);
    k_gemm2m<<<(N + 63) / 64, 256, 0, stream>>>(h1b, Wf2, bq2, bk2, bv2, bs2, qs2, k82, v2, N);
    k_agg2<<<(N + 3) / 4, 256, 0, stream>>>(qs2, k82, v2, row_ptr, boff, colb, (float*)d_out, N);
}

// Round 19
// 154.040 us; speedup vs baseline: 1.0207x; 1.0207x over previous
//
#include <hip/hip_runtime.h>
#include <hip/hip_bf16.h>
#include <hip/hip_fp8.h>

#define N_NODES 50000
#define N_EDGES 800000
#define HB 3125   // hist/scatter blocks: 800000/256
#define GA 1562   // gemm1 blocks in D2 (16 rows each)
#define GB2 1563  // gemm1 blocks in D4 ; GA+GB2 = 3125 = 50000/16
#define NBS 49    // scan blocks: ceil(50000/1024)

static constexpr float SCALE = 0.17677669529663687f; // 1/sqrt(32)

typedef __attribute__((ext_vector_type(8))) short bf16x8;
typedef __attribute__((ext_vector_type(4))) float f32x4;
typedef __attribute__((ext_vector_type(2))) float f32x2;
#define MFMA16 __builtin_amdgcn_mfma_f32_16x16x32_bf16
#define CVT8 __builtin_amdgcn_cvt_pk_f32_fp8

static __device__ inline unsigned short f2bf(float f) {
    __hip_bfloat16 h = __float2bfloat16(f);
    return __builtin_bit_cast(unsigned short, h);
}
static __device__ inline unsigned char f2fp8(float f) {
    __hip_fp8_e4m3 h(f); // OCP e4m3fn, RNE
    return __builtin_bit_cast(unsigned char, h);
}
// packed pair of bf16 (one u32) -> f32x2
static __device__ inline f32x2 bfp2(unsigned u) {
    f32x2 r;
    r[0] = __uint_as_float(u << 16);
    r[1] = __uint_as_float(u & 0xffff0000u);
    return r;
}

// ---------------- 16-row GEMM1 block (low-VGPR: acc[4] per column-half) ----------------

static __device__ __forceinline__ void gemm16(
    int rb, unsigned char* smem,
    const float* __restrict__ x, const unsigned short* __restrict__ Wf1,
    const float* __restrict__ bq, const float* __restrict__ bk,
    const float* __restrict__ bv, const float* __restrict__ bs,
    unsigned short* __restrict__ qs1, unsigned char* __restrict__ kv8)
{
    int w = threadIdx.x >> 6;
    int l = threadIdx.x & 63;
    int lr = l & 15, lk = l >> 4;
    unsigned short* xs = (unsigned short*)smem;      // [16][72]
    unsigned char* ep = smem + 2560;                 // wave w: ep + w*2304
    {
        int row = threadIdx.x >> 4, c = (threadIdx.x & 15) * 4;
        float4 f = *(const float4*)(x + (size_t)(rb + row) * 64 + c);
        unsigned short* dp = xs + row * 72 + c;
        dp[0] = f2bf(f.x); dp[1] = f2bf(f.y); dp[2] = f2bf(f.z); dp[3] = f2bf(f.w);
    }
    __syncthreads();
    bf16x8 a0 = *(const bf16x8*)(xs + lr * 72 + lk * 8);
    bf16x8 a1 = *(const bf16x8*)(xs + lr * 72 + 32 + lk * 8);
    const float* bptr = (w == 0) ? bq : (w == 1) ? bk : (w == 2) ? bv : bs;
#pragma unroll
    for (int hf = 0; hf < 2; ++hf) {
        f32x4 acc[4];
#pragma unroll
        for (int nt4 = 0; nt4 < 4; ++nt4) acc[nt4] = (f32x4){0.f, 0.f, 0.f, 0.f};
#pragma unroll
        for (int nt4 = 0; nt4 < 4; ++nt4) {
            int nt = hf * 4 + nt4;
            bf16x8 b0 = *(const bf16x8*)(Wf1 + (size_t)((w * 8 + nt) * 1024) + l * 8);
            bf16x8 b1 = *(const bf16x8*)(Wf1 + (size_t)((w * 8 + nt) * 1024 + 512) + l * 8);
            acc[nt4] = MFMA16(a0, b0, acc[nt4], 0, 0, 0);
            acc[nt4] = MFMA16(a1, b1, acc[nt4], 0, 0, 0);
        }
        if (w == 1 || w == 2) { // k,v -> fp8 into interleaved kv8 (groups 8hf..8hf+8)
            unsigned char* lb = ep + w * 2304;   // [16][72] bytes
#pragma unroll
            for (int nt4 = 0; nt4 < 4; ++nt4) {
                float bias = bptr[hf * 64 + nt4 * 16 + lr];
#pragma unroll
                for (int i = 0; i < 4; ++i)
                    lb[(lk * 4 + i) * 72 + nt4 * 16 + lr] = f2fp8(acc[nt4][i] + bias);
            }
            int voff = (w == 2) ? 8 : 0;
            int g = lr & 7, b = lr >> 3;
#pragma unroll
            for (int p = 0; p < 2; ++p) {
                int rl = p * 8 + lk * 2 + b;
                uint2 val = *(const uint2*)(lb + rl * 72 + g * 8);
                *(uint2*)(kv8 + (size_t)(rb + rl) * 256 + (hf * 8 + g) * 16 + voff) = val;
            }
        } else {                // q,s -> bf16 qs1 (cols hf*64..hf*64+64)
            unsigned short* ls = (unsigned short*)(ep + w * 2304); // [16][72] shorts -> 2304B ✓
#pragma unroll
            for (int nt4 = 0; nt4 < 4; ++nt4) {
                float bias = bptr[hf * 64 + nt4 * 16 + lr];
#pragma unroll
                for (int i = 0; i < 4; ++i)
                    ls[(lk * 4 + i) * 72 + nt4 * 16 + lr] = f2bf(acc[nt4][i] + bias);
            }
            int base = (w == 0) ? 0 : 128;
#pragma unroll
            for (int p = 0; p < 4; ++p) {
                int rl = p * 4 + lk;
                uint2 val = *(const uint2*)(ls + rl * 72 + lr * 4);
                *(uint2*)(qs1 + (size_t)(rb + rl) * 256 + base + hf * 64 + lr * 4) = val;
            }
        }
    }
}

// ---------------- D1: weight fragments + cnt8/ctr zero ----------------

__global__ __launch_bounds__(256) void k_wf(
    const float* __restrict__ Wq1, const float* __restrict__ Wk1,
    const float* __restrict__ Wv1, const float* __restrict__ Ws1,
    const float* __restrict__ Wq2, const float* __restrict__ Wk2,
    const float* __restrict__ Wv2, const float* __restrict__ Ws2,
    unsigned short* __restrict__ Wf1, unsigned short* __restrict__ Wf2,
    int* __restrict__ cnt8)
{
    int id = blockIdx.x * 256 + threadIdx.x;
    if (id < N_NODES * 8 + 64) cnt8[id] = 0;  // 8 planes + ctr tail
    if (id < 32768) {
        int j = id & 7, l = (id >> 3) & 63, ks = (id >> 9) & 1, nt = (id >> 10) & 7, m = (id >> 13) & 3;
        const float* W = (m == 0) ? Wq1 : (m == 1) ? Wk1 : (m == 2) ? Wv1 : Ws1;
        int k = ks * 32 + ((l >> 4) << 3) + j;
        int c = nt * 16 + (l & 15);
        Wf1[id] = f2bf(W[k * 128 + c]);
    } else if (id < 49152) {
        int id2 = id - 32768;
        int j = id2 & 7, l = (id2 >> 3) & 63, ks = (id2 >> 9) & 3, g = (id2 >> 11) & 7;
        int m = g >> 1, t = g & 1;
        const float* W = (m == 0) ? Wq2 : (m == 1) ? Wk2 : (m == 2) ? Wv2 : Ws2;
        int k = ks * 32 + ((l >> 4) << 3) + j;
        int c = t * 16 + (l & 15);
        Wf2[id2] = f2bf(W[k * 32 + c]);
    }
}

// ---------------- D2: XCD-local-plane hist (blocks 0..HB) || GEMM1 rows [0, GA*16) ----------------
// Plane index = blockIdx&7 (NOT tid&7 as in R18): block dispatch round-robins across
// XCDs, so each plane's cache lines are touched by (approximately) ONE XCD only ->
// no cross-XCD line ping-pong on the device-scope atomics. Correctness is
// mapping-independent; this is purely a locality hint.

__global__ __launch_bounds__(256) void k_hg2(
    const int* __restrict__ dst, int* __restrict__ cnt8, int* __restrict__ rank,
    const float* __restrict__ x, const unsigned short* __restrict__ Wf1,
    const float* __restrict__ bq, const float* __restrict__ bk,
    const float* __restrict__ bv, const float* __restrict__ bs,
    unsigned short* __restrict__ qs1, unsigned char* __restrict__ kv8)
{
    __shared__ unsigned char smem[2560 + 4 * 2304];
    if (blockIdx.x < HB) {
        int e = blockIdx.x * 256 + threadIdx.x; // E exact multiple of 256
        rank[e] = atomicAdd(&cnt8[(blockIdx.x & 7) * N_NODES + dst[e]], 1);
        return;
    }
    gemm16((blockIdx.x - HB) * 16, smem, x, Wf1, bq, bk, bv, bs, qs1, kv8);
}

// ---------------- D3: scan over plane counts ----------------
// row[v] = block-local exclusive prefix of node totals (as before).
// cnt8[r][v] is overwritten with (row_local + plane prefix) so scatter needs ONE gather.

__global__ __launch_bounds__(256) void k_scan(int* __restrict__ cnt8,
                                              int* __restrict__ row,
                                              int* __restrict__ bsum,
                                              int* __restrict__ boff,
                                              int* __restrict__ ctr, int n) {
    __shared__ int wsum[4];
    __shared__ int lastBlk;
    int t = threadIdx.x;
    int base = blockIdx.x * 1024 + t * 4;
    int c[4][8];
    int tot[4];
#pragma unroll
    for (int i = 0; i < 4; ++i) {
        int v = base + i;
        tot[i] = 0;
        if (v < n) {
#pragma unroll
            for (int r = 0; r < 8; ++r) {
                c[i][r] = cnt8[r * N_NODES + v];
                tot[i] += c[i][r];
            }
        }
    }
    int s = tot[0] + tot[1] + tot[2] + tot[3];
    int lane = t & 63, wid = t >> 6;
    int sc = s;
#pragma unroll
    for (int d = 1; d < 64; d <<= 1) {
        int o = __shfl_up(sc, d);
        if (lane >= d) sc += o;
    }
    if (lane == 63) wsum[wid] = sc;
    __syncthreads();
    int woff = 0;
    for (int w = 0; w < wid; ++w) woff += wsum[w];
    int run = woff + sc - s; // exclusive prefix for this thread's first node
#pragma unroll
    for (int i = 0; i < 4; ++i) {
        int v = base + i;
        if (v < n) {
            row[v] = run;
#pragma unroll
            for (int r = 0; r < 8; ++r) {
                cnt8[r * N_NODES + v] = run;
                run += c[i][r];
            }
        }
    }
    if (t == 255) {
        bsum[blockIdx.x] = woff + sc;
        __threadfence();
        lastBlk = (atomicAdd(ctr, 1) == NBS - 1);
    }
    __syncthreads();
    if (lastBlk && t < 64) {
        __threadfence();
        int v = (t < NBS) ? ((volatile int*)bsum)[t] : 0;
        int sc2 = v;
#pragma unroll
        for (int d = 1; d < 64; d <<= 1) {
            int o = __shfl_up(sc2, d);
            if (t >= d) sc2 += o;
        }
        boff[t] = sc2 - v; // exclusive block offset
        if (t == (N_NODES >> 10)) row[N_NODES] = N_EDGES - (sc2 - v);
    }
}

// ---------------- D4: GEMM1 rows [GA*16, 50000) (blocks 0..GB2) || scatter ----------------
// scatter: plane for edge e is the plane its hist block used: (e>>8)&7.

__global__ __launch_bounds__(256) void k_sg2(
    const int* __restrict__ src, const int* __restrict__ dst,
    const int* __restrict__ cnt8, const int* __restrict__ boff,
    const int* __restrict__ rank, int* __restrict__ col,
    const float* __restrict__ x, const unsigned short* __restrict__ Wf1,
    const float* __restrict__ bq, const float* __restrict__ bk,
    const float* __restrict__ bv, const float* __restrict__ bs,
    unsigned short* __restrict__ qs1, unsigned char* __restrict__ kv8)
{
    __shared__ unsigned char smem[2560 + 4 * 2304];
    if (blockIdx.x >= GB2) {
        int e = (blockIdx.x - GB2) * 256 + threadIdx.x;
        int de = dst[e];
        col[cnt8[((e >> 8) & 7) * N_NODES + de] + boff[de >> 10] + rank[e]] = src[e];
        return;
    }
    gemm16((GA + blockIdx.x) * 16, smem, x, Wf1, bq, bk, bv, bs, qs1, kv8);
}

// ---------------- GEMM 2 (MFMA): h1b[N,128]bf16 @ {Wq,Wk,Wv,Ws}[128,32] + b ----------------

__global__ __launch_bounds__(256) void k_gemm2m(
    const unsigned short* __restrict__ h1b, const unsigned short* __restrict__ Wf2,
    const float* __restrict__ bq, const float* __restrict__ bk,
    const float* __restrict__ bv, const float* __restrict__ bs,
    unsigned short* __restrict__ qs2, unsigned char* __restrict__ k82,
    unsigned short* __restrict__ v2, int n)
{
    __shared__ unsigned short lds[4][32][72]; // 18.4 KB
    int w = threadIdx.x >> 6;
    int l = threadIdx.x & 63;
    int half = w & 1;
    int rb = blockIdx.x * 64 + (w >> 1) * 32;
    int lr = l & 15, lk = l >> 4;
    f32x4 acc[2][4];
#pragma unroll
    for (int mt = 0; mt < 2; ++mt)
#pragma unroll
        for (int nt = 0; nt < 4; ++nt) acc[mt][nt] = (f32x4){0.f, 0.f, 0.f, 0.f};
#pragma unroll
    for (int ks = 0; ks < 4; ++ks) {
        bf16x8 a[2];
#pragma unroll
        for (int mt = 0; mt < 2; ++mt) {
            int r = rb + mt * 16 + lr;
            if (r >= n) r = n - 1;
            a[mt] = *(const bf16x8*)(h1b + (size_t)r * 128 + ks * 32 + lk * 8);
        }
#pragma unroll
        for (int nt = 0; nt < 4; ++nt) {
            int g = half * 4 + nt;
            bf16x8 b = *(const bf16x8*)(Wf2 + (size_t)((g * 4 + ks) * 512 + l * 8));
            acc[0][nt] = MFMA16(a[0], b, acc[0][nt], 0, 0, 0);
            acc[1][nt] = MFMA16(a[1], b, acc[1][nt], 0, 0, 0);
        }
    }
#pragma unroll
    for (int nt = 0; nt < 4; ++nt) {
        int g = half * 4 + nt;
        int mat = g >> 1;
        int c = (g * 16 + lr) & 31;
        const float* bp = (mat == 0) ? bq : (mat == 1) ? bk : (mat == 2) ? bv : bs;
        float bias = bp[c];
#pragma unroll
        for (int mt = 0; mt < 2; ++mt)
#pragma unroll
            for (int i = 0; i < 4; ++i)
                lds[w][mt * 16 + lk * 4 + i][nt * 16 + lr] = f2bf(acc[mt][nt][i] + bias);
    }
    int rl8 = l >> 3, ci = (l & 7) * 4;
#pragma unroll
    for (int p = 0; p < 4; ++p) {
        int rl = p * 8 + rl8;
        int r = rb + rl;
        if (r < n) {
            uint2 va = *(const uint2*)&lds[w][rl][ci];
            uint2 vb = *(const uint2*)&lds[w][rl][32 + ci];
            if (half == 0) {
                *(uint2*)(qs2 + (size_t)r * 64 + ci) = va;              // q bf16
                unsigned pk =                                            // k -> fp8
                      (unsigned)f2fp8(__uint_as_float(vb.x << 16))
                    | ((unsigned)f2fp8(__uint_as_float(vb.x & 0xffff0000u)) << 8)
                    | ((unsigned)f2fp8(__uint_as_float(vb.y << 16)) << 16)
                    | ((unsigned)f2fp8(__uint_as_float(vb.y & 0xffff0000u)) << 24);
                *(unsigned*)(k82 + (size_t)r * 32 + ci) = pk;
            } else {
                *(uint2*)(v2 + (size_t)r * 32 + ci) = va;               // v bf16
                *(uint2*)(qs2 + (size_t)r * 64 + 32 + ci) = vb;         // s bf16
            }
        }
    }
}

// ---------------- Layer-1 attention aggregate (measured floor: do not touch) ----------------

__global__ __launch_bounds__(256) void k_agg1(
    const unsigned short* __restrict__ qs1, const unsigned char* __restrict__ kv8,
    const int* __restrict__ row, const int* __restrict__ boff,
    const int* __restrict__ col, uint4* __restrict__ h1b, int n)
{
    int i = blockIdx.x * 4 + (threadIdx.x >> 6);
    if (i >= n) return;
    int lane = threadIdx.x & 63;
    int slot = lane >> 4, w = lane & 15;
    f32x2 q2[4];
    {
        uint4 qu = *(const uint4*)(qs1 + (size_t)i * 256 + w * 8);
        q2[0] = bfp2(qu.x); q2[1] = bfp2(qu.y); q2[2] = bfp2(qu.z); q2[3] = bfp2(qu.w);
    }
    f32x2 acc2[4] = {};
    float d = 0.f;
    int s = row[i] + boff[i >> 10];
    int e = row[i + 1] + boff[(i + 1) >> 10];
    for (int t = s; t < e; t += 8) {
        int ta = t + slot, tb = t + 4 + slot;
        bool va = ta < e, vb = tb < e;
        int ja = col[va ? ta : s];
        int jb = col[vb ? tb : s];
        uint4 A = *(const uint4*)(kv8 + (size_t)ja * 256 + w * 16);
        uint4 B = *(const uint4*)(kv8 + (size_t)jb * 256 + w * 16);
        f32x2 pa = CVT8(A.x, false) * q2[0];
        pa += CVT8(A.x, true)  * q2[1];
        pa += CVT8(A.y, false) * q2[2];
        pa += CVT8(A.y, true)  * q2[3];
        f32x2 pb = CVT8(B.x, false) * q2[0];
        pb += CVT8(B.x, true)  * q2[1];
        pb += CVT8(B.y, false) * q2[2];
        pb += CVT8(B.y, true)  * q2[3];
        float la = pa[0] + pa[1];
        float lb = pb[0] + pb[1];
        la += __shfl_xor(la, 1);  lb += __shfl_xor(lb, 1);
        la += __shfl_xor(la, 2);  lb += __shfl_xor(lb, 2);
        float wa = va ? __expf(la * SCALE) : 0.f;
        float wb = vb ? __expf(lb * SCALE) : 0.f;
        d += wa + wb;
        f32x2 wa2 = (f32x2){wa, wa};
        f32x2 wb2 = (f32x2){wb, wb};
        acc2[0] += wa2 * CVT8(A.z, false);
        acc2[1] += wa2 * CVT8(A.z, true);
        acc2[2] += wa2 * CVT8(A.w, false);
        acc2[3] += wa2 * CVT8(A.w, true);
        acc2[0] += wb2 * CVT8(B.z, false);
        acc2[1] += wb2 * CVT8(B.z, true);
        acc2[2] += wb2 * CVT8(B.w, false);
        acc2[3] += wb2 * CVT8(B.w, true);
    }
    float acc[8] = {acc2[0][0], acc2[0][1], acc2[1][0], acc2[1][1],
                    acc2[2][0], acc2[2][1], acc2[3][0], acc2[3][1]};
#pragma unroll
    for (int m = 16; m <= 32; m <<= 1) {
        d += __shfl_xor(d, m);
#pragma unroll
        for (int c = 0; c < 8; ++c) acc[c] += __shfl_xor(acc[c], m);
    }
    if (slot == 0) {
        float inv = (d > 0.f) ? 1.f / d : 0.f;
        uint4 su = *(const uint4*)(qs1 + (size_t)i * 256 + 128 + w * 8);
        f32x2 sv[4] = {bfp2(su.x), bfp2(su.y), bfp2(su.z), bfp2(su.w)};
        unsigned o[4];
#pragma unroll
        for (int p = 0; p < 4; ++p) {
            float rx = acc[2 * p] * inv + sv[p][0];
            float ry = acc[2 * p + 1] * inv + sv[p][1];
            rx = (rx > 0.f) ? rx : expm1f(rx); // ELU
            ry = (ry > 0.f) ? ry : expm1f(ry);
            o[p] = ((unsigned)f2bf(ry) << 16) | (unsigned)f2bf(rx);
        }
        h1b[(size_t)i * 16 + w] = make_uint4(o[0], o[1], o[2], o[3]);
    }
}

// ---------------- Layer-2 attention aggregate ----------------

__global__ __launch_bounds__(256) void k_agg2(
    const unsigned short* __restrict__ qs2, const unsigned char* __restrict__ k82,
    const unsigned short* __restrict__ v2,
    const int* __restrict__ row, const int* __restrict__ boff,
    const int* __restrict__ col, float* __restrict__ out, int n)
{
    int i = blockIdx.x * 4 + (threadIdx.x >> 6);
    if (i >= n) return;
    int lane = threadIdx.x & 63;
    int slot = lane >> 2, qr = lane & 3;
    f32x2 q2[4];
    {
        uint4 qu = *(const uint4*)(qs2 + (size_t)i * 64 + qr * 8);
        q2[0] = bfp2(qu.x); q2[1] = bfp2(qu.y); q2[2] = bfp2(qu.z); q2[3] = bfp2(qu.w);
    }
    f32x2 acc2[4] = {};
    float d = 0.f;
    int s = row[i] + boff[i >> 10];
    int e = row[i + 1] + boff[(i + 1) >> 10];
    for (int t = s; t < e; t += 16) {
        int te = t + slot;
        bool va = te < e;
        int j = col[va ? te : s];
        uint2 ku = *(const uint2*)(k82 + (size_t)j * 32 + qr * 8);
        uint4 vu = *(const uint4*)(v2 + (size_t)j * 32 + qr * 8);
        f32x2 pp = CVT8(ku.x, false) * q2[0];
        pp += CVT8(ku.x, true)  * q2[1];
        pp += CVT8(ku.y, false) * q2[2];
        pp += CVT8(ku.y, true)  * q2[3];
        float lg = pp[0] + pp[1];
        lg += __shfl_xor(lg, 1);
        lg += __shfl_xor(lg, 2);
        float wv = va ? __expf(lg * SCALE) : 0.f;
        d += wv;
        f32x2 w2 = (f32x2){wv, wv};
        acc2[0] += w2 * bfp2(vu.x);
        acc2[1] += w2 * bfp2(vu.y);
        acc2[2] += w2 * bfp2(vu.z);
        acc2[3] += w2 * bfp2(vu.w);
    }
    float acc[8] = {acc2[0][0], acc2[0][1], acc2[1][0], acc2[1][1],
                    acc2[2][0], acc2[2][1], acc2[3][0], acc2[3][1]};
#pragma unroll
    for (int m = 4; m <= 32; m <<= 1) {
        d += __shfl_xor(d, m);
#pragma unroll
        for (int c = 0; c < 8; ++c) acc[c] += __shfl_xor(acc[c], m);
    }
    if (slot == 0) {
        float inv = (d > 0.f) ? 1.f / d : 0.f;
        uint4 su = *(const uint4*)(qs2 + (size_t)i * 64 + 32 + qr * 8);
        f32x2 sv[4] = {bfp2(su.x), bfp2(su.y), bfp2(su.z), bfp2(su.w)};
        float4 o0, o1;
        o0.x = acc[0] * inv + sv[0][0];
        o0.y = acc[1] * inv + sv[0][1];
        o0.z = acc[2] * inv + sv[1][0];
        o0.w = acc[3] * inv + sv[1][1];
        o1.x = acc[4] * inv + sv[2][0];
        o1.y = acc[5] * inv + sv[2][1];
        o1.z = acc[6] * inv + sv[3][0];
        o1.w = acc[7] * inv + sv[3][1];
        *(float4*)&out[(size_t)i * 32 + qr * 8] = o0;
        *(float4*)&out[(size_t)i * 32 + qr * 8 + 4] = o1;
    }
}

// ---------------- launch ----------------

extern "C" void kernel_launch(void* const* d_in, const int* in_sizes, int n_in,
                              void* d_out, int out_size, void* d_ws, size_t ws_size,
                              hipStream_t stream)
{
    const int N = N_NODES, E = N_EDGES;
    const float* x   = (const float*)d_in[0];
    const int* edge  = (const int*)d_in[1];
    const int* src   = edge;       // edge_index[0]
    const int* dst   = edge + E;   // edge_index[1]
    const float* Wq1 = (const float*)d_in[2];  const float* bq1 = (const float*)d_in[3];
    const float* Wk1 = (const float*)d_in[4];  const float* bk1 = (const float*)d_in[5];
    const float* Wv1 = (const float*)d_in[6];  const float* bv1 = (const float*)d_in[7];
    const float* Ws1 = (const float*)d_in[8];  const float* bs1 = (const float*)d_in[9];
    const float* Wq2 = (const float*)d_in[10]; const float* bq2 = (const float*)d_in[11];
    const float* Wk2 = (const float*)d_in[12]; const float* bk2 = (const float*)d_in[13];
    const float* Wv2 = (const float*)d_in[14]; const float* bv2 = (const float*)d_in[15];
    const float* Ws2 = (const float*)d_in[16]; const float* bs2 = (const float*)d_in[17];

    char* ws = (char*)d_ws;
    size_t off = 0;
    auto alloc = [&](size_t bytes) -> void* {
        void* p = ws + off;
        off += (bytes + 255) & ~(size_t)255;
        return p;
    };
    unsigned short* qs1 = (unsigned short*)alloc((size_t)N * 256 * 2); // 25.6 MB
    unsigned char*  kv8 = (unsigned char*)alloc((size_t)N * 256);      // 12.8 MB (k,v interleaved fp8)
    unsigned short* h1b = (unsigned short*)alloc((size_t)N * 128 * 2); // 12.8 MB
    unsigned short* qs2 = (unsigned short*)alloc((size_t)N * 64 * 2);  //  6.4 MB
    unsigned char*  k82 = (unsigned char*)alloc((size_t)N * 32);       //  1.6 MB (fp8 k2)
    unsigned short* v2  = (unsigned short*)alloc((size_t)N * 32 * 2);  //  3.2 MB (bf16 v2)
    unsigned short* Wf1 = (unsigned short*)alloc(32768 * 2);
    unsigned short* Wf2 = (unsigned short*)alloc(16384 * 2);
    int* row_ptr  = (int*)alloc((size_t)(N + 1) * 4);
    int* cnt8     = (int*)alloc((size_t)(N * 8 + 64) * 4); // 8 planes + ctr
    int* ctr      = cnt8 + N * 8;
    int* rank     = (int*)alloc((size_t)E * 4);
    int* colb     = (int*)alloc((size_t)E * 4);
    int* bsum     = (int*)alloc(64 * 4);
    int* boff     = (int*)alloc(64 * 4);

    int WFB = (N * 8 + 64 + 255) / 256; // 1563 blocks: cnt8 zero + both wfrag ranges

    k_wf<<<WFB, 256, 0, stream>>>(Wq1, Wk1, Wv1, Ws1, Wq2, Wk2, Wv2, Ws2,
                                  Wf1, Wf2, cnt8);
    k_hg2<<<HB + GA, 256, 0, stream>>>(dst, cnt8, rank,
                                       x, Wf1, bq1, bk1, bv1, bs1, qs1, kv8);
    k_scan<<<NBS, 256, 0, stream>>>(cnt8, row_ptr, bsum, boff, ctr, N);
    k_sg2<<<GB2 + HB, 256, 0, stream>>>(src, dst, cnt8, boff, rank, colb,
                                        x, Wf1, bq1, bk1, bv1, bs1, qs1, kv8);
    k_agg1<<<(N + 3) / 4, 256, 0, stream>>>(qs1, kv8, row_ptr, boff, colb, (uint4*)h1b, N);
    k_gemm2m<<<(N + 63) / 64, 256, 0, stream>>>(h1b, Wf2, bq2, bk2, bv2, bs2, qs2, k82, v2, N);
    k_agg2<<<(N + 3) / 4, 256, 0, stream>>>(qs2, k82, v2, row_ptr, boff, colb, (float*)d_out, N);
}